// Round 6
// baseline (89.695 us; speedup 1.0000x reference)
//
#include <hip/hip_runtime.h>
#include <hip/hip_bf16.h>

#define NQ     4000
#define DMODEL 256
#define NHEAD  8
#define NLVL   4
#define NPT    4
#define DHEAD  32
#define LENIN  37440
#define NOFF   384
#define NATT   128
#define NPROJ  512   // NOFF + NATT

typedef _Float16 f16x8 __attribute__((ext_vector_type(8)));
typedef _Float16 f16x4 __attribute__((ext_vector_type(4)));
typedef float    f32x4 __attribute__((ext_vector_type(4)));

// ------------------------------------- all weight casts+transposes, 1 launch
__global__ __launch_bounds__(256) void cast_transpose_all(
    const float* __restrict__ wv, const float* __restrict__ wo,
    const float* __restrict__ wa, const float* __restrict__ wu,
    _Float16* __restrict__ wvT, _Float16* __restrict__ catT,
    _Float16* __restrict__ wuT)
{
    __shared__ float t[64][65];
    const int xt = blockIdx.x, kt = blockIdx.y;
    const float* W; _Float16* WT; int ncols, col0, nbase;
    if (xt < 4)       { W = wv; WT = wvT;  ncols = 256; col0 = xt * 64;        nbase = col0; }
    else if (xt < 10) { W = wo; WT = catT; ncols = 384; col0 = (xt - 4) * 64;  nbase = col0; }
    else if (xt < 12) { W = wa; WT = catT; ncols = 128; col0 = (xt - 10) * 64; nbase = 384 + col0; }
    else              { W = wu; WT = wuT;  ncols = 256; col0 = (xt - 12) * 64; nbase = col0; }

    const int by = kt * 64;           // k-range
    const int tid = threadIdx.x;
    const int c = tid & 63, r0 = tid >> 6;
    #pragma unroll
    for (int i = 0; i < 16; ++i) {
        int r = r0 + i * 4;
        t[r][c] = W[(size_t)(by + r) * ncols + col0 + c];
    }
    __syncthreads();
    #pragma unroll
    for (int i = 0; i < 16; ++i) {
        int n = r0 + i * 4;
        WT[(size_t)(nbase + n) * DMODEL + by + c] = (_Float16)t[c][n];
    }
}

// ------------------------------------------------- generic f16 MFMA GEMM
// C = A[M,256] @ BT[N,256]^T + bias.  96 rows x 256 cols per block.
// LDS double-buffered, ONE barrier per K-step. 256 threads = 4 waves;
// wave w owns cols [64w, 64w+64); 6x4 16x16x32 fragments per wave.
#define GBM 96
#define LDH 40   // padded LDS row (halfs)

template <typename InT, typename OutT, bool HM>
__global__ __launch_bounds__(256) void gemm_mfma(
    const InT* __restrict__ A, const _Float16* __restrict__ BT,
    const float* __restrict__ bias0, const float* __restrict__ bias1,
    int split, OutT* __restrict__ C, int M, int ldc)
{
    __shared__ __align__(16) _Float16 As[2][GBM][LDH];
    __shared__ __align__(16) _Float16 Bs[2][256][LDH];
    const int tid  = threadIdx.x;
    const int wave = tid >> 6, lane = tid & 63;
    const int brow = blockIdx.x * GBM;
    const int ncb  = blockIdx.y * 256;
    const int l15 = lane & 15, l16 = lane >> 4;

    // A staging: 96 rows x 32 k = 768 4-elem slots; 3 per thread.
    int arow[3], akq[3];
    const InT* aptr[3];
    #pragma unroll
    for (int i = 0; i < 3; ++i) {
        int slot = tid + 256 * i;
        arow[i] = slot >> 3; akq[i] = (slot & 7) * 4;
        int rg = brow + arow[i]; if (rg >= M) rg = M - 1;
        aptr[i] = A + (size_t)rg * DMODEL + akq[i];
    }
    // B staging: 256 n x 32 k = 1024 8-half chunks; 4 per thread.
    const _Float16* bptr[4];
    int bn[4], bkc[4];
    #pragma unroll
    for (int j = 0; j < 4; ++j) {
        int id = tid + 256 * j;
        bn[j] = id >> 2; bkc[j] = (id & 3) * 8;
        bptr[j] = BT + (size_t)(ncb + bn[j]) * DMODEL + bkc[j];
    }

    f32x4 acc[6][4] = {};   // [mi][ni]
    float4 a32[3]; f16x4 a16[3];
    f16x8 bh[4];

    // prefetch K-step 0
    #pragma unroll
    for (int i = 0; i < 3; ++i) {
        if constexpr (sizeof(InT) == 2) a16[i] = *(const f16x4*)(const void*)aptr[i];
        else                            a32[i] = *(const float4*)(const void*)aptr[i];
    }
    #pragma unroll
    for (int j = 0; j < 4; ++j) bh[j] = *(const f16x8*)bptr[j];
    // store tile 0 into buf 0
    #pragma unroll
    for (int i = 0; i < 3; ++i) {
        f16x4 h;
        if constexpr (sizeof(InT) == 2) h = a16[i];
        else { h[0] = (_Float16)a32[i].x; h[1] = (_Float16)a32[i].y;
               h[2] = (_Float16)a32[i].z; h[3] = (_Float16)a32[i].w; }
        *(f16x4*)&As[0][arow[i]][akq[i]] = h;
    }
    #pragma unroll
    for (int j = 0; j < 4; ++j) *(f16x8*)&Bs[0][bn[j]][bkc[j]] = bh[j];

    #pragma unroll
    for (int k = 0; k < 8; ++k) {
        const int cur = k & 1, nxt = cur ^ 1;
        if (k < 7) {    // issue next tile's global loads (latency hidden by MFMA)
            int koff = (k + 1) * 32;
            #pragma unroll
            for (int i = 0; i < 3; ++i) {
                if constexpr (sizeof(InT) == 2) a16[i] = *(const f16x4*)(const void*)(aptr[i] + koff);
                else                            a32[i] = *(const float4*)(const void*)(aptr[i] + koff);
            }
            #pragma unroll
            for (int j = 0; j < 4; ++j) bh[j] = *(const f16x8*)(bptr[j] + koff);
        }
        __syncthreads();   // buf[cur] fully written (by end of previous iter)

        f16x8 af[6], bf[4];
        #pragma unroll
        for (int mi = 0; mi < 6; ++mi)
            af[mi] = *(const f16x8*)&As[cur][mi * 16 + l15][l16 * 8];
        #pragma unroll
        for (int ni = 0; ni < 4; ++ni)
            bf[ni] = *(const f16x8*)&Bs[cur][wave * 64 + ni * 16 + l15][l16 * 8];
        #pragma unroll
        for (int mi = 0; mi < 6; ++mi)
            #pragma unroll
            for (int ni = 0; ni < 4; ++ni)
                acc[mi][ni] = __builtin_amdgcn_mfma_f32_16x16x32_f16(
                    af[mi], bf[ni], acc[mi][ni], 0, 0, 0);

        if (k < 7) {    // write next tile into the other buffer (no barrier needed)
            #pragma unroll
            for (int i = 0; i < 3; ++i) {
                f16x4 h;
                if constexpr (sizeof(InT) == 2) h = a16[i];
                else { h[0] = (_Float16)a32[i].x; h[1] = (_Float16)a32[i].y;
                       h[2] = (_Float16)a32[i].z; h[3] = (_Float16)a32[i].w; }
                *(f16x4*)&As[nxt][arow[i]][akq[i]] = h;
            }
            #pragma unroll
            for (int j = 0; j < 4; ++j) *(f16x8*)&Bs[nxt][bn[j]][bkc[j]] = bh[j];
        }
    }

    #pragma unroll
    for (int ni = 0; ni < 4; ++ni) {
        int col = ncb + wave * 64 + ni * 16 + l15;
        float b = (col < split) ? bias0[col] : bias1[col - split];
        #pragma unroll
        for (int mi = 0; mi < 6; ++mi)
            #pragma unroll
            for (int j = 0; j < 4; ++j) {
                int row = brow + mi * 16 + l16 * 4 + j;
                if (row < M) {
                    float v = acc[mi][ni][j] + b;
                    if constexpr (HM) {
                        int h = col >> 5, d = col & 31;
                        C[((size_t)h * LENIN + row) * DHEAD + d] = (OutT)v;
                    } else {
                        C[(size_t)row * ldc + col] = (OutT)v;
                    }
                }
            }
    }
}

// ---------------- fused: loc + softmax + corner precompute + gather (4 q/blk)
// One wave per query. value is head-major: [h][cell][32ch] f16.
// Gather: lane = h*8+s; chunk=s&3 owns 8 channels (16B), half=s>>2 covers
// 4 corners; halves combined via shfl_xor(4). 64 x 16B loads per lane.
__global__ __launch_bounds__(256) void sample_fused3(
    const _Float16* __restrict__ value, const float* __restrict__ proj,
    const float* __restrict__ refpts, _Float16* __restrict__ oat)
{
    __shared__ float loc_s[4][NOFF];
    __shared__ float aw_s[4][NATT];
    __shared__ uint2 cw_s[4][1056];     // [h*132 + pt*8 + c]

    const int tid  = threadIdx.x;
    const int wv   = tid >> 6, lane = tid & 63;
    const int q    = blockIdx.x * 4 + wv;
    const float* pq = proj + (size_t)q * NPROJ;

    // ---- phase 0: locations + softmax
    #pragma unroll
    for (int i = 0; i < 8; ++i) {
        int t = i * 64 + lane;
        float v = pq[t];
        if (t < NOFF) {
            int t2 = t / 3, lvl = (t2 >> 2) & 3, c = t - t2 * 3;
            float norm = (float)(32 >> lvl);
            loc_s[wv][t] = refpts[((size_t)q * NLVL + lvl) * 3 + c] + v / norm;
        } else {
            float m = v;
            #pragma unroll
            for (int o = 8; o >= 1; o >>= 1) m = fmaxf(m, __shfl_xor(m, o, 16));
            float e = expf(v - m);
            float s = e;
            #pragma unroll
            for (int o = 8; o >= 1; o >>= 1) s += __shfl_xor(s, o, 16);
            aw_s[wv][t - NOFF] = e / s;
        }
    }
    __syncthreads();

    // ---- phase 1: per-corner byte address (head-major) + weight
    #pragma unroll
    for (int i = 0; i < 16; ++i) {
        int id = i * 64 + lane;            // h*128 + pt*8 + c
        int h = id >> 7, pt = (id >> 3) & 15, c = id & 7;
        int lvl = pt >> 2;
        int S = 32 >> lvl;
        float Sf = (float)S;
        int base = (lvl == 0) ? 0 : (lvl == 1) ? 32768 : (lvl == 2) ? 36864 : 37376;

        float lx = loc_s[wv][h * 48 + pt * 3 + 0];
        float ly = loc_s[wv][h * 48 + pt * 3 + 1];
        float lz = loc_s[wv][h * 48 + pt * 3 + 2];
        float aw = aw_s[wv][h * 16 + pt];

        float x = lx * Sf - 0.5f, y = ly * Sf - 0.5f, z = lz * Sf - 0.5f;
        float x0f = floorf(x), y0f = floorf(y), z0f = floorf(z);
        float fx = x - x0f, fy = y - y0f, fz = z - z0f;
        int dx = c & 1, dy = (c >> 1) & 1, dz = c >> 2;
        int xi = (int)x0f + dx, yi = (int)y0f + dy, zi = (int)z0f + dz;
        float wx = dx ? fx : 1.f - fx;
        float wy = dy ? fy : 1.f - fy;
        float wz = dz ? fz : 1.f - fz;
        bool valid = (unsigned)xi < (unsigned)S &&
                     (unsigned)yi < (unsigned)S &&
                     (unsigned)zi < (unsigned)S;
        float w = valid ? wx * wy * wz * aw : 0.f;
        int xc = min(max(xi, 0), S - 1);
        int yc = min(max(yi, 0), S - 1);
        int zc = min(max(zi, 0), S - 1);
        int idx = (zc * S + yc) * S + xc;
        unsigned addr = (unsigned)(h * LENIN + base + idx) * 64u;  // bytes
        cw_s[wv][h * 132 + pt * 8 + c] = make_uint2(addr, __float_as_uint(w));
    }
    __syncthreads();

    // ---- phase 2: gather, 16B per load
    const int h = lane >> 3, s = lane & 7;
    const int chunk = s & 3, half4 = (s >> 2) * 4;
    const char* vb = (const char*)value + chunk * 16;
    const uint2* cw = &cw_s[wv][h * 132];

    float acc[8] = {};
    #pragma unroll 4
    for (int pt = 0; pt < 16; ++pt) {
        uint4 ra = *(const uint4*)&cw[pt * 8 + half4];       // corners half4+0,+1
        uint4 rb = *(const uint4*)&cw[pt * 8 + half4 + 2];   // corners half4+2,+3
        {
            f16x8 v = *(const f16x8*)(vb + ra.x); float w = __uint_as_float(ra.y);
            #pragma unroll
            for (int j = 0; j < 8; ++j) acc[j] += w * (float)v[j];
        }
        {
            f16x8 v = *(const f16x8*)(vb + ra.z); float w = __uint_as_float(ra.w);
            #pragma unroll
            for (int j = 0; j < 8; ++j) acc[j] += w * (float)v[j];
        }
        {
            f16x8 v = *(const f16x8*)(vb + rb.x); float w = __uint_as_float(rb.y);
            #pragma unroll
            for (int j = 0; j < 8; ++j) acc[j] += w * (float)v[j];
        }
        {
            f16x8 v = *(const f16x8*)(vb + rb.z); float w = __uint_as_float(rb.w);
            #pragma unroll
            for (int j = 0; j < 8; ++j) acc[j] += w * (float)v[j];
        }
    }
    // combine the two corner-halves (lanes s and s^4 own same channels)
    #pragma unroll
    for (int j = 0; j < 8; ++j) acc[j] += __shfl_xor(acc[j], 4);

    if (s < 4) {
        f16x8 r;
        #pragma unroll
        for (int j = 0; j < 8; ++j) r[j] = (_Float16)acc[j];
        *(f16x8*)&oat[(size_t)q * DMODEL + h * DHEAD + chunk * 8] = r;
    }
}

extern "C" void kernel_launch(void* const* d_in, const int* in_sizes, int n_in,
                              void* d_out, int out_size, void* d_ws, size_t ws_size,
                              hipStream_t stream) {
    const float* query         = (const float*)d_in[0];
    const float* refpts        = (const float*)d_in[1];
    const float* input_flatten = (const float*)d_in[2];
    const float* w_value       = (const float*)d_in[3];
    const float* b_value       = (const float*)d_in[4];
    const float* w_off         = (const float*)d_in[5];
    const float* b_off         = (const float*)d_in[6];
    const float* w_attn        = (const float*)d_in[7];
    const float* b_attn        = (const float*)d_in[8];
    const float* w_out         = (const float*)d_in[9];
    const float* b_out         = (const float*)d_in[10];

    _Float16* valueH = (_Float16*)d_ws;                    // head-major [h][cell][32]
    _Float16* wvT    = valueH + (size_t)LENIN * DMODEL;
    _Float16* catT   = wvT + 256 * 256;
    _Float16* wuT    = catT + 512 * 256;
    float*    proj   = (float*)(wuT + 256 * 256);
    _Float16* oatH   = (_Float16*)(proj + (size_t)NQ * NPROJ);
    // total ~30 MB of workspace

    cast_transpose_all<<<dim3(16, 4), 256, 0, stream>>>(
        w_value, w_off, w_attn, w_out, wvT, catT, wuT);

    gemm_mfma<float, _Float16, true><<<dim3(LENIN / GBM, 1), 256, 0, stream>>>(
        input_flatten, wvT, b_value, b_value, 256, valueH, LENIN, DMODEL);

    gemm_mfma<float, float, false><<<dim3((NQ + GBM - 1) / GBM, 2), 256, 0, stream>>>(
        query, catT, b_off, b_attn, NOFF, proj, NQ, NPROJ);

    sample_fused3<<<NQ / 4, 256, 0, stream>>>(valueH, proj, refpts, oatH);

    gemm_mfma<_Float16, float, false><<<dim3((NQ + GBM - 1) / GBM, 1), 256, 0, stream>>>(
        oatH, wuT, b_out, b_out, 256, (float*)d_out, NQ, DMODEL);
}

// Round 7
// 82.039 us; speedup vs baseline: 1.0933x; 1.0933x over previous
//
#include <hip/hip_runtime.h>
#include <hip/hip_bf16.h>

#define NQ     4000
#define DMODEL 256
#define NHEAD  8
#define NLVL   4
#define NPT    4
#define DHEAD  32
#define LENIN  37440
#define NOFF   384
#define NATT   128
#define NPROJ  512   // NOFF + NATT

typedef _Float16 f16x8 __attribute__((ext_vector_type(8)));
typedef _Float16 f16x4 __attribute__((ext_vector_type(4)));
typedef float    f32x4 __attribute__((ext_vector_type(4)));

// ------------------------------------- all weight casts+transposes, 1 launch
__global__ __launch_bounds__(256) void cast_transpose_all(
    const float* __restrict__ wv, const float* __restrict__ wo,
    const float* __restrict__ wa, const float* __restrict__ wu,
    _Float16* __restrict__ wvT, _Float16* __restrict__ catT,
    _Float16* __restrict__ wuT)
{
    __shared__ float t[64][65];
    const int xt = blockIdx.x, kt = blockIdx.y;
    const float* W; _Float16* WT; int ncols, col0, nbase;
    if (xt < 4)       { W = wv; WT = wvT;  ncols = 256; col0 = xt * 64;        nbase = col0; }
    else if (xt < 10) { W = wo; WT = catT; ncols = 384; col0 = (xt - 4) * 64;  nbase = col0; }
    else if (xt < 12) { W = wa; WT = catT; ncols = 128; col0 = (xt - 10) * 64; nbase = 384 + col0; }
    else              { W = wu; WT = wuT;  ncols = 256; col0 = (xt - 12) * 64; nbase = col0; }

    const int by = kt * 64;           // k-range
    const int tid = threadIdx.x;
    const int c = tid & 63, r0 = tid >> 6;
    #pragma unroll
    for (int i = 0; i < 16; ++i) {
        int r = r0 + i * 4;
        t[r][c] = W[(size_t)(by + r) * ncols + col0 + c];
    }
    __syncthreads();
    #pragma unroll
    for (int i = 0; i < 16; ++i) {
        int n = r0 + i * 4;
        WT[(size_t)(nbase + n) * DMODEL + by + c] = (_Float16)t[c][n];
    }
}

// ------------------------------------------------- generic f16 MFMA GEMM
// C = A[M,256] @ BT[N,256]^T + bias.  64 rows x 256 cols per block.
// Single LDS buffer (25.6KB -> 6 blocks/CU), register prefetch of next
// K-step issued after the first barrier (T14 issue-early / write-late).
#define LDH 40   // padded LDS row (halfs)

template <typename InT, typename OutT, bool HM>
__global__ __launch_bounds__(256) void gemm_mfma(
    const InT* __restrict__ A, const _Float16* __restrict__ BT,
    const float* __restrict__ bias0, const float* __restrict__ bias1,
    int split, OutT* __restrict__ C, int M, int ldc)
{
    __shared__ __align__(16) _Float16 As[64][LDH];
    __shared__ __align__(16) _Float16 Bs[256][LDH];
    const int tid  = threadIdx.x;
    const int wave = tid >> 6, lane = tid & 63;
    const int brow = blockIdx.x * 64;
    const int ncb  = blockIdx.y * 256;
    const int l15 = lane & 15, l16 = lane >> 4;

    const int arow = tid >> 2, akq = (tid & 3) * 8;
    int arg = brow + arow; if (arg >= M) arg = M - 1;
    const InT* aptr = A + (size_t)arg * DMODEL + akq;

    const _Float16* bptr[4];
    int bn[4], bkc[4];
    #pragma unroll
    for (int j = 0; j < 4; ++j) {
        int id = tid + 256 * j;            // chunk id = n*4 + kc
        bn[j] = id >> 2; bkc[j] = (id & 3) * 8;
        bptr[j] = BT + (size_t)(ncb + bn[j]) * DMODEL + bkc[j];
    }

    f32x4 acc[4][4] = {};   // [mi][ni]
    float4 a0, a1; f16x8 ah;
    f16x8 bh[4];

    // prefetch K-step 0
    if constexpr (sizeof(InT) == 2) {
        ah = *(const f16x8*)(const void*)aptr;
    } else {
        a0 = *(const float4*)(const void*)aptr;
        a1 = *(const float4*)(const void*)(aptr + 4);
    }
    #pragma unroll
    for (int j = 0; j < 4; ++j) bh[j] = *(const f16x8*)bptr[j];

    for (int k0 = 0; k0 < DMODEL; k0 += 32) {
        // write staged registers to LDS
        if constexpr (sizeof(InT) == 2) {
            *(f16x8*)&As[arow][akq] = ah;
        } else {
            f16x8 h;
            h[0] = (_Float16)a0.x; h[1] = (_Float16)a0.y;
            h[2] = (_Float16)a0.z; h[3] = (_Float16)a0.w;
            h[4] = (_Float16)a1.x; h[5] = (_Float16)a1.y;
            h[6] = (_Float16)a1.z; h[7] = (_Float16)a1.w;
            *(f16x8*)&As[arow][akq] = h;
        }
        #pragma unroll
        for (int j = 0; j < 4; ++j) *(f16x8*)&Bs[bn[j]][bkc[j]] = bh[j];
        __syncthreads();

        // issue next K-step's global loads before the MFMA cluster
        if (k0 + 32 < DMODEL) {
            if constexpr (sizeof(InT) == 2) {
                ah = *(const f16x8*)(const void*)(aptr + k0 + 32);
            } else {
                a0 = *(const float4*)(const void*)(aptr + k0 + 32);
                a1 = *(const float4*)(const void*)(aptr + k0 + 36);
            }
            #pragma unroll
            for (int j = 0; j < 4; ++j) bh[j] = *(const f16x8*)(bptr[j] + k0 + 32);
        }

        f16x8 af[4], bf[4];
        #pragma unroll
        for (int mi = 0; mi < 4; ++mi)
            af[mi] = *(const f16x8*)&As[mi * 16 + l15][l16 * 8];
        #pragma unroll
        for (int ni = 0; ni < 4; ++ni)
            bf[ni] = *(const f16x8*)&Bs[wave * 64 + ni * 16 + l15][l16 * 8];
        #pragma unroll
        for (int mi = 0; mi < 4; ++mi)
            #pragma unroll
            for (int ni = 0; ni < 4; ++ni)
                acc[mi][ni] = __builtin_amdgcn_mfma_f32_16x16x32_f16(
                    af[mi], bf[ni], acc[mi][ni], 0, 0, 0);
        __syncthreads();
    }

    #pragma unroll
    for (int ni = 0; ni < 4; ++ni) {
        int col = ncb + wave * 64 + ni * 16 + l15;
        float b = (col < split) ? bias0[col] : bias1[col - split];
        #pragma unroll
        for (int mi = 0; mi < 4; ++mi)
            #pragma unroll
            for (int j = 0; j < 4; ++j) {
                int row = brow + mi * 16 + l16 * 4 + j;
                if (row < M) {
                    float v = acc[mi][ni][j] + b;
                    if constexpr (HM) {
                        int h = col >> 5, d = col & 31;
                        C[((size_t)h * LENIN + row) * DHEAD + d] = (OutT)v;
                    } else {
                        C[(size_t)row * ldc + col] = (OutT)v;
                    }
                }
            }
    }
}

// ---------------- fused: loc + softmax + corner precompute + gather (4 q/blk)
// One wave per query. value is head-major: [h][cell][32ch] f16.
// Gather: lane = h*8+s; chunk=s&3 owns 8 channels (16B), half=s>>2 covers
// 4 corners; halves combined via shfl_xor(4). 64 x 16B loads per lane.
__global__ __launch_bounds__(256) void sample_fused3(
    const _Float16* __restrict__ value, const float* __restrict__ proj,
    const float* __restrict__ refpts, _Float16* __restrict__ oat)
{
    __shared__ float loc_s[4][NOFF];
    __shared__ float aw_s[4][NATT];
    __shared__ uint2 cw_s[4][1056];     // [h*132 + pt*8 + c]

    const int tid  = threadIdx.x;
    const int wv   = tid >> 6, lane = tid & 63;
    const int q    = blockIdx.x * 4 + wv;
    const float* pq = proj + (size_t)q * NPROJ;

    // ---- phase 0: locations + softmax
    #pragma unroll
    for (int i = 0; i < 8; ++i) {
        int t = i * 64 + lane;
        float v = pq[t];
        if (t < NOFF) {
            int t2 = t / 3, lvl = (t2 >> 2) & 3, c = t - t2 * 3;
            float norm = (float)(32 >> lvl);
            loc_s[wv][t] = refpts[((size_t)q * NLVL + lvl) * 3 + c] + v / norm;
        } else {
            float m = v;
            #pragma unroll
            for (int o = 8; o >= 1; o >>= 1) m = fmaxf(m, __shfl_xor(m, o, 16));
            float e = expf(v - m);
            float s = e;
            #pragma unroll
            for (int o = 8; o >= 1; o >>= 1) s += __shfl_xor(s, o, 16);
            aw_s[wv][t - NOFF] = e / s;
        }
    }
    __syncthreads();

    // ---- phase 1: per-corner byte address (head-major) + weight
    #pragma unroll
    for (int i = 0; i < 16; ++i) {
        int id = i * 64 + lane;            // h*128 + pt*8 + c
        int h = id >> 7, pt = (id >> 3) & 15, c = id & 7;
        int lvl = pt >> 2;
        int S = 32 >> lvl;
        float Sf = (float)S;
        int base = (lvl == 0) ? 0 : (lvl == 1) ? 32768 : (lvl == 2) ? 36864 : 37376;

        float lx = loc_s[wv][h * 48 + pt * 3 + 0];
        float ly = loc_s[wv][h * 48 + pt * 3 + 1];
        float lz = loc_s[wv][h * 48 + pt * 3 + 2];
        float aw = aw_s[wv][h * 16 + pt];

        float x = lx * Sf - 0.5f, y = ly * Sf - 0.5f, z = lz * Sf - 0.5f;
        float x0f = floorf(x), y0f = floorf(y), z0f = floorf(z);
        float fx = x - x0f, fy = y - y0f, fz = z - z0f;
        int dx = c & 1, dy = (c >> 1) & 1, dz = c >> 2;
        int xi = (int)x0f + dx, yi = (int)y0f + dy, zi = (int)z0f + dz;
        float wx = dx ? fx : 1.f - fx;
        float wy = dy ? fy : 1.f - fy;
        float wz = dz ? fz : 1.f - fz;
        bool valid = (unsigned)xi < (unsigned)S &&
                     (unsigned)yi < (unsigned)S &&
                     (unsigned)zi < (unsigned)S;
        float w = valid ? wx * wy * wz * aw : 0.f;
        int xc = min(max(xi, 0), S - 1);
        int yc = min(max(yi, 0), S - 1);
        int zc = min(max(zi, 0), S - 1);
        int idx = (zc * S + yc) * S + xc;
        unsigned addr = (unsigned)(h * LENIN + base + idx) * 64u;  // bytes
        cw_s[wv][h * 132 + pt * 8 + c] = make_uint2(addr, __float_as_uint(w));
    }
    __syncthreads();

    // ---- phase 2: gather, 16B per load
    const int h = lane >> 3, s = lane & 7;
    const int chunk = s & 3, half4 = (s >> 2) * 4;
    const char* vb = (const char*)value + chunk * 16;
    const uint2* cw = &cw_s[wv][h * 132];

    float acc[8] = {};
    #pragma unroll 4
    for (int pt = 0; pt < 16; ++pt) {
        uint4 ra = *(const uint4*)&cw[pt * 8 + half4];       // corners half4+0,+1
        uint4 rb = *(const uint4*)&cw[pt * 8 + half4 + 2];   // corners half4+2,+3
        {
            f16x8 v = *(const f16x8*)(vb + ra.x); float w = __uint_as_float(ra.y);
            #pragma unroll
            for (int j = 0; j < 8; ++j) acc[j] += w * (float)v[j];
        }
        {
            f16x8 v = *(const f16x8*)(vb + ra.z); float w = __uint_as_float(ra.w);
            #pragma unroll
            for (int j = 0; j < 8; ++j) acc[j] += w * (float)v[j];
        }
        {
            f16x8 v = *(const f16x8*)(vb + rb.x); float w = __uint_as_float(rb.y);
            #pragma unroll
            for (int j = 0; j < 8; ++j) acc[j] += w * (float)v[j];
        }
        {
            f16x8 v = *(const f16x8*)(vb + rb.z); float w = __uint_as_float(rb.w);
            #pragma unroll
            for (int j = 0; j < 8; ++j) acc[j] += w * (float)v[j];
        }
    }
    // combine the two corner-halves (lanes s and s^4 own same channels)
    #pragma unroll
    for (int j = 0; j < 8; ++j) acc[j] += __shfl_xor(acc[j], 4);

    if (s < 4) {
        f16x8 r;
        #pragma unroll
        for (int j = 0; j < 8; ++j) r[j] = (_Float16)acc[j];
        *(f16x8*)&oat[(size_t)q * DMODEL + h * DHEAD + chunk * 8] = r;
    }
}

extern "C" void kernel_launch(void* const* d_in, const int* in_sizes, int n_in,
                              void* d_out, int out_size, void* d_ws, size_t ws_size,
                              hipStream_t stream) {
    const float* query         = (const float*)d_in[0];
    const float* refpts        = (const float*)d_in[1];
    const float* input_flatten = (const float*)d_in[2];
    const float* w_value       = (const float*)d_in[3];
    const float* b_value       = (const float*)d_in[4];
    const float* w_off         = (const float*)d_in[5];
    const float* b_off         = (const float*)d_in[6];
    const float* w_attn        = (const float*)d_in[7];
    const float* b_attn        = (const float*)d_in[8];
    const float* w_out         = (const float*)d_in[9];
    const float* b_out         = (const float*)d_in[10];

    _Float16* valueH = (_Float16*)d_ws;                    // head-major [h][cell][32]
    _Float16* wvT    = valueH + (size_t)LENIN * DMODEL;
    _Float16* catT   = wvT + 256 * 256;
    _Float16* wuT    = catT + 512 * 256;
    float*    proj   = (float*)(wuT + 256 * 256);
    _Float16* oatH   = (_Float16*)(proj + (size_t)NQ * NPROJ);
    // total ~30 MB of workspace

    cast_transpose_all<<<dim3(16, 4), 256, 0, stream>>>(
        w_value, w_off, w_attn, w_out, wvT, catT, wuT);

    gemm_mfma<float, _Float16, true><<<dim3(LENIN / 64, 1), 256, 0, stream>>>(
        input_flatten, wvT, b_value, b_value, 256, valueH, LENIN, DMODEL);

    gemm_mfma<float, float, false><<<dim3((NQ + 63) / 64, 2), 256, 0, stream>>>(
        query, catT, b_off, b_attn, NOFF, proj, NQ, NPROJ);

    sample_fused3<<<NQ / 4, 256, 0, stream>>>(valueH, proj, refpts, oatH);

    gemm_mfma<_Float16, float, false><<<dim3((NQ + 63) / 64, 1), 256, 0, stream>>>(
        oatH, wuT, b_out, b_out, 256, (float*)d_out, NQ, DMODEL);
}

// Round 8
// 68.812 us; speedup vs baseline: 1.3035x; 1.1922x over previous
//
#include <hip/hip_runtime.h>
#include <hip/hip_bf16.h>

#define NQ     4000
#define DMODEL 256
#define NHEAD  8
#define NLVL   4
#define NPT    4
#define DHEAD  32
#define LENIN  37440
#define NOFF   384
#define NATT   128
#define NPROJ  512   // NOFF + NATT

#define NVBLK  (LENIN / 64)            // 585 value-role blocks
#define NQBLK  ((NQ + 63) / 64)        // 63 row tiles for query-side GEMMs
#define LDH    40                      // padded LDS row (halfs) for GEMM tiles
#define LDSW   132                     // padded LDS row (halfs) for C bounce

typedef _Float16 f16x8 __attribute__((ext_vector_type(8)));
typedef _Float16 f16x4 __attribute__((ext_vector_type(4)));
typedef float    f32x4 __attribute__((ext_vector_type(4)));

// ------------------------------------- all weight casts+transposes, 1 launch
__global__ __launch_bounds__(256) void cast_transpose_all(
    const float* __restrict__ wv, const float* __restrict__ wo,
    const float* __restrict__ wa, const float* __restrict__ wu,
    _Float16* __restrict__ wvT, _Float16* __restrict__ catT,
    _Float16* __restrict__ wuT)
{
    __shared__ float t[64][65];
    const int xt = blockIdx.x, kt = blockIdx.y;
    const float* W; _Float16* WT; int ncols, col0, nbase;
    if (xt < 4)       { W = wv; WT = wvT;  ncols = 256; col0 = xt * 64;        nbase = col0; }
    else if (xt < 10) { W = wo; WT = catT; ncols = 384; col0 = (xt - 4) * 64;  nbase = col0; }
    else if (xt < 12) { W = wa; WT = catT; ncols = 128; col0 = (xt - 10) * 64; nbase = 384 + col0; }
    else              { W = wu; WT = wuT;  ncols = 256; col0 = (xt - 12) * 64; nbase = col0; }

    const int by = kt * 64;           // k-range
    const int tid = threadIdx.x;
    const int c = tid & 63, r0 = tid >> 6;
    #pragma unroll
    for (int i = 0; i < 16; ++i) {
        int r = r0 + i * 4;
        t[r][c] = W[(size_t)(by + r) * ncols + col0 + c];
    }
    __syncthreads();
    #pragma unroll
    for (int i = 0; i < 16; ++i) {
        int n = r0 + i * 4;
        WT[(size_t)(nbase + n) * DMODEL + by + c] = (_Float16)t[c][n];
    }
}

// -------------------------------------------- merged front GEMM (fp32 input)
// Role A (bid < NVBLK):  valueH(f16, head-major) = input_flatten @ wvT^T + bv
//                        epilogue via LDS bounce -> coalesced stores.
// Role B (bid >= NVBLK): proj(f32) = query @ catT^T + [b_off|b_attn].
__global__ __launch_bounds__(256) void gemm_front(
    const float* __restrict__ Aval, const float* __restrict__ query,
    const _Float16* __restrict__ wvT, const _Float16* __restrict__ catT,
    const float* __restrict__ bval, const float* __restrict__ boff,
    const float* __restrict__ batt,
    _Float16* __restrict__ valueH, float* __restrict__ proj)
{
    __shared__ __align__(16) char smem[25600];
    _Float16 (*As)[LDH] = (_Float16 (*)[LDH])smem;                 // 64 x 40
    _Float16 (*Bs)[LDH] = (_Float16 (*)[LDH])(smem + 64 * LDH * 2);// 256 x 40

    const int tid  = threadIdx.x;
    const int wave = tid >> 6, lane = tid & 63;
    const int l15 = lane & 15, l16 = lane >> 4;

    const int  bid   = blockIdx.x;
    const bool isval = (bid < NVBLK);
    const float* A; const _Float16* BT; int brow, ncb, M;
    if (isval) { A = Aval;  BT = wvT;  brow = bid * 64;  ncb = 0;  M = LENIN; }
    else       { int idx = bid - NVBLK; A = query; BT = catT;
                 brow = (idx >> 1) * 64; ncb = (idx & 1) * 256; M = NQ; }

    const int arow = tid >> 2, akq = (tid & 3) * 8;
    int arg = brow + arow; if (arg >= M) arg = M - 1;
    const float* aptr = A + (size_t)arg * DMODEL + akq;

    const _Float16* bptr[4];
    int bn[4], bkc[4];
    #pragma unroll
    for (int j = 0; j < 4; ++j) {
        int id = tid + 256 * j;            // chunk id = n*4 + kc
        bn[j] = id >> 2; bkc[j] = (id & 3) * 8;
        bptr[j] = BT + (size_t)(ncb + bn[j]) * DMODEL + bkc[j];
    }

    f32x4 acc[4][4] = {};   // [mi][ni]
    float4 a0, a1;
    f16x8 bh[4];

    a0 = *(const float4*)(const void*)aptr;
    a1 = *(const float4*)(const void*)(aptr + 4);
    #pragma unroll
    for (int j = 0; j < 4; ++j) bh[j] = *(const f16x8*)bptr[j];

    for (int k0 = 0; k0 < DMODEL; k0 += 32) {
        {
            f16x8 h;
            h[0] = (_Float16)a0.x; h[1] = (_Float16)a0.y;
            h[2] = (_Float16)a0.z; h[3] = (_Float16)a0.w;
            h[4] = (_Float16)a1.x; h[5] = (_Float16)a1.y;
            h[6] = (_Float16)a1.z; h[7] = (_Float16)a1.w;
            *(f16x8*)&As[arow][akq] = h;
        }
        #pragma unroll
        for (int j = 0; j < 4; ++j) *(f16x8*)&Bs[bn[j]][bkc[j]] = bh[j];
        __syncthreads();

        if (k0 + 32 < DMODEL) {   // issue next K-step's loads before MFMA
            a0 = *(const float4*)(const void*)(aptr + k0 + 32);
            a1 = *(const float4*)(const void*)(aptr + k0 + 36);
            #pragma unroll
            for (int j = 0; j < 4; ++j) bh[j] = *(const f16x8*)(bptr[j] + k0 + 32);
        }

        f16x8 af[4], bf[4];
        #pragma unroll
        for (int mi = 0; mi < 4; ++mi)
            af[mi] = *(const f16x8*)&As[mi * 16 + l15][l16 * 8];
        #pragma unroll
        for (int ni = 0; ni < 4; ++ni)
            bf[ni] = *(const f16x8*)&Bs[wave * 64 + ni * 16 + l15][l16 * 8];
        #pragma unroll
        for (int mi = 0; mi < 4; ++mi)
            #pragma unroll
            for (int ni = 0; ni < 4; ++ni)
                acc[mi][ni] = __builtin_amdgcn_mfma_f32_16x16x32_f16(
                    af[mi], bf[ni], acc[mi][ni], 0, 0, 0);
        __syncthreads();
    }

    if (isval) {
        // ---- epilogue A: LDS bounce -> coalesced head-major stores
        _Float16 (*out_s)[LDSW] = (_Float16 (*)[LDSW])smem;
        const int cell = tid >> 2, dchunk = tid & 3;
        #pragma unroll
        for (int hh = 0; hh < 2; ++hh) {
            if ((wave >> 1) == hh) {
                int cb = (wave & 1) * 64;
                #pragma unroll
                for (int ni = 0; ni < 4; ++ni) {
                    int col = wave * 64 + ni * 16 + l15;
                    float b = bval[col];
                    #pragma unroll
                    for (int mi = 0; mi < 4; ++mi)
                        #pragma unroll
                        for (int j = 0; j < 4; ++j)
                            out_s[mi * 16 + l16 * 4 + j][cb + ni * 16 + l15] =
                                (_Float16)(acc[mi][ni][j] + b);
                }
            }
            __syncthreads();
            #pragma unroll
            for (int h2 = 0; h2 < 4; ++h2) {
                int h = hh * 4 + h2;
                f16x4 lo = *(const f16x4*)&out_s[cell][h2 * 32 + dchunk * 8];
                f16x4 hi = *(const f16x4*)&out_s[cell][h2 * 32 + dchunk * 8 + 4];
                size_t base = ((size_t)h * LENIN + brow + cell) * DHEAD + dchunk * 8;
                *(f16x4*)&valueH[base]     = lo;
                *(f16x4*)&valueH[base + 4] = hi;
            }
            __syncthreads();
        }
    } else {
        // ---- epilogue B: direct f32 stores to proj
        #pragma unroll
        for (int ni = 0; ni < 4; ++ni) {
            int col = ncb + wave * 64 + ni * 16 + l15;
            float b = (col < NOFF) ? boff[col] : batt[col - NOFF];
            #pragma unroll
            for (int mi = 0; mi < 4; ++mi)
                #pragma unroll
                for (int j = 0; j < 4; ++j) {
                    int row = brow + mi * 16 + l16 * 4 + j;
                    if (row < NQ)
                        proj[(size_t)row * NPROJ + col] = acc[mi][ni][j] + b;
                }
        }
    }
}

// ---------------- fused: loc + softmax + corner precompute + gather (4 q/blk)
// One wave per query. value is head-major: [h][cell][32ch] f16.
__global__ __launch_bounds__(256) void sample_fused3(
    const _Float16* __restrict__ value, const float* __restrict__ proj,
    const float* __restrict__ refpts, _Float16* __restrict__ oat)
{
    __shared__ float loc_s[4][NOFF];
    __shared__ float aw_s[4][NATT];
    __shared__ uint2 cw_s[4][1056];     // [h*132 + pt*8 + c]

    const int tid  = threadIdx.x;
    const int wv   = tid >> 6, lane = tid & 63;
    const int q    = blockIdx.x * 4 + wv;
    const float* pq = proj + (size_t)q * NPROJ;

    // ---- phase 0: locations + softmax
    #pragma unroll
    for (int i = 0; i < 8; ++i) {
        int t = i * 64 + lane;
        float v = pq[t];
        if (t < NOFF) {
            int t2 = t / 3, lvl = (t2 >> 2) & 3, c = t - t2 * 3;
            float norm = (float)(32 >> lvl);
            loc_s[wv][t] = refpts[((size_t)q * NLVL + lvl) * 3 + c] + v / norm;
        } else {
            float m = v;
            #pragma unroll
            for (int o = 8; o >= 1; o >>= 1) m = fmaxf(m, __shfl_xor(m, o, 16));
            float e = expf(v - m);
            float s = e;
            #pragma unroll
            for (int o = 8; o >= 1; o >>= 1) s += __shfl_xor(s, o, 16);
            aw_s[wv][t - NOFF] = e / s;
        }
    }
    __syncthreads();

    // ---- phase 1: per-corner byte address (head-major) + weight
    #pragma unroll
    for (int i = 0; i < 16; ++i) {
        int id = i * 64 + lane;            // h*128 + pt*8 + c
        int h = id >> 7, pt = (id >> 3) & 15, c = id & 7;
        int lvl = pt >> 2;
        int S = 32 >> lvl;
        float Sf = (float)S;
        int base = (lvl == 0) ? 0 : (lvl == 1) ? 32768 : (lvl == 2) ? 36864 : 37376;

        float lx = loc_s[wv][h * 48 + pt * 3 + 0];
        float ly = loc_s[wv][h * 48 + pt * 3 + 1];
        float lz = loc_s[wv][h * 48 + pt * 3 + 2];
        float aw = aw_s[wv][h * 16 + pt];

        float x = lx * Sf - 0.5f, y = ly * Sf - 0.5f, z = lz * Sf - 0.5f;
        float x0f = floorf(x), y0f = floorf(y), z0f = floorf(z);
        float fx = x - x0f, fy = y - y0f, fz = z - z0f;
        int dx = c & 1, dy = (c >> 1) & 1, dz = c >> 2;
        int xi = (int)x0f + dx, yi = (int)y0f + dy, zi = (int)z0f + dz;
        float wx = dx ? fx : 1.f - fx;
        float wy = dy ? fy : 1.f - fy;
        float wz = dz ? fz : 1.f - fz;
        bool valid = (unsigned)xi < (unsigned)S &&
                     (unsigned)yi < (unsigned)S &&
                     (unsigned)zi < (unsigned)S;
        float w = valid ? wx * wy * wz * aw : 0.f;
        int xc = min(max(xi, 0), S - 1);
        int yc = min(max(yi, 0), S - 1);
        int zc = min(max(zi, 0), S - 1);
        int idx = (zc * S + yc) * S + xc;
        unsigned addr = (unsigned)(h * LENIN + base + idx) * 64u;  // bytes
        cw_s[wv][h * 132 + pt * 8 + c] = make_uint2(addr, __float_as_uint(w));
    }
    __syncthreads();

    // ---- phase 2: gather, 16B per load
    const int h = lane >> 3, s = lane & 7;
    const int chunk = s & 3, half4 = (s >> 2) * 4;
    const char* vb = (const char*)value + chunk * 16;
    const uint2* cw = &cw_s[wv][h * 132];

    float acc[8] = {};
    #pragma unroll 4
    for (int pt = 0; pt < 16; ++pt) {
        uint4 ra = *(const uint4*)&cw[pt * 8 + half4];       // corners half4+0,+1
        uint4 rb = *(const uint4*)&cw[pt * 8 + half4 + 2];   // corners half4+2,+3
        {
            f16x8 v = *(const f16x8*)(vb + ra.x); float w = __uint_as_float(ra.y);
            #pragma unroll
            for (int j = 0; j < 8; ++j) acc[j] += w * (float)v[j];
        }
        {
            f16x8 v = *(const f16x8*)(vb + ra.z); float w = __uint_as_float(ra.w);
            #pragma unroll
            for (int j = 0; j < 8; ++j) acc[j] += w * (float)v[j];
        }
        {
            f16x8 v = *(const f16x8*)(vb + rb.x); float w = __uint_as_float(rb.y);
            #pragma unroll
            for (int j = 0; j < 8; ++j) acc[j] += w * (float)v[j];
        }
        {
            f16x8 v = *(const f16x8*)(vb + rb.z); float w = __uint_as_float(rb.w);
            #pragma unroll
            for (int j = 0; j < 8; ++j) acc[j] += w * (float)v[j];
        }
    }
    // combine the two corner-halves (lanes s and s^4 own same channels)
    #pragma unroll
    for (int j = 0; j < 8; ++j) acc[j] += __shfl_xor(acc[j], 4);

    if (s < 4) {
        f16x8 r;
        #pragma unroll
        for (int j = 0; j < 8; ++j) r[j] = (_Float16)acc[j];
        *(f16x8*)&oat[(size_t)q * DMODEL + h * DHEAD + chunk * 8] = r;
    }
}

// ------------------------------------------- output projection (f16 in, MFMA)
__global__ __launch_bounds__(256) void gemm_out(
    const _Float16* __restrict__ A, const _Float16* __restrict__ BT,
    const float* __restrict__ bias, float* __restrict__ C)
{
    __shared__ __align__(16) _Float16 As[64][LDH];
    __shared__ __align__(16) _Float16 Bs[256][LDH];
    const int tid  = threadIdx.x;
    const int wave = tid >> 6, lane = tid & 63;
    const int brow = blockIdx.x * 64;
    const int l15 = lane & 15, l16 = lane >> 4;

    const int arow = tid >> 2, akq = (tid & 3) * 8;
    int arg = brow + arow; if (arg >= NQ) arg = NQ - 1;
    const _Float16* aptr = A + (size_t)arg * DMODEL + akq;

    const _Float16* bptr[4];
    int bn[4], bkc[4];
    #pragma unroll
    for (int j = 0; j < 4; ++j) {
        int id = tid + 256 * j;
        bn[j] = id >> 2; bkc[j] = (id & 3) * 8;
        bptr[j] = BT + (size_t)bn[j] * DMODEL + bkc[j];
    }

    f32x4 acc[4][4] = {};
    f16x8 ah, bh[4];
    ah = *(const f16x8*)(const void*)aptr;
    #pragma unroll
    for (int j = 0; j < 4; ++j) bh[j] = *(const f16x8*)bptr[j];

    for (int k0 = 0; k0 < DMODEL; k0 += 32) {
        *(f16x8*)&As[arow][akq] = ah;
        #pragma unroll
        for (int j = 0; j < 4; ++j) *(f16x8*)&Bs[bn[j]][bkc[j]] = bh[j];
        __syncthreads();

        if (k0 + 32 < DMODEL) {
            ah = *(const f16x8*)(const void*)(aptr + k0 + 32);
            #pragma unroll
            for (int j = 0; j < 4; ++j) bh[j] = *(const f16x8*)(bptr[j] + k0 + 32);
        }

        f16x8 af[4], bf[4];
        #pragma unroll
        for (int mi = 0; mi < 4; ++mi)
            af[mi] = *(const f16x8*)&As[mi * 16 + l15][l16 * 8];
        #pragma unroll
        for (int ni = 0; ni < 4; ++ni)
            bf[ni] = *(const f16x8*)&Bs[wave * 64 + ni * 16 + l15][l16 * 8];
        #pragma unroll
        for (int mi = 0; mi < 4; ++mi)
            #pragma unroll
            for (int ni = 0; ni < 4; ++ni)
                acc[mi][ni] = __builtin_amdgcn_mfma_f32_16x16x32_f16(
                    af[mi], bf[ni], acc[mi][ni], 0, 0, 0);
        __syncthreads();
    }

    #pragma unroll
    for (int ni = 0; ni < 4; ++ni) {
        int col = wave * 64 + ni * 16 + l15;
        float b = bias[col];
        #pragma unroll
        for (int mi = 0; mi < 4; ++mi)
            #pragma unroll
            for (int j = 0; j < 4; ++j) {
                int row = brow + mi * 16 + l16 * 4 + j;
                if (row < NQ)
                    C[(size_t)row * DMODEL + col] = acc[mi][ni][j] + b;
            }
    }
}

extern "C" void kernel_launch(void* const* d_in, const int* in_sizes, int n_in,
                              void* d_out, int out_size, void* d_ws, size_t ws_size,
                              hipStream_t stream) {
    const float* query         = (const float*)d_in[0];
    const float* refpts        = (const float*)d_in[1];
    const float* input_flatten = (const float*)d_in[2];
    const float* w_value       = (const float*)d_in[3];
    const float* b_value       = (const float*)d_in[4];
    const float* w_off         = (const float*)d_in[5];
    const float* b_off         = (const float*)d_in[6];
    const float* w_attn        = (const float*)d_in[7];
    const float* b_attn        = (const float*)d_in[8];
    const float* w_out         = (const float*)d_in[9];
    const float* b_out         = (const float*)d_in[10];

    _Float16* valueH = (_Float16*)d_ws;                    // head-major [h][cell][32]
    _Float16* wvT    = valueH + (size_t)LENIN * DMODEL;
    _Float16* catT   = wvT + 256 * 256;
    _Float16* wuT    = catT + 512 * 256;
    float*    proj   = (float*)(wuT + 256 * 256);
    _Float16* oatH   = (_Float16*)(proj + (size_t)NQ * NPROJ);
    // total ~30 MB of workspace

    cast_transpose_all<<<dim3(16, 4), 256, 0, stream>>>(
        w_value, w_off, w_attn, w_out, wvT, catT, wuT);

    gemm_front<<<NVBLK + NQBLK * 2, 256, 0, stream>>>(
        input_flatten, query, wvT, catT, b_value, b_off, b_attn, valueH, proj);

    sample_fused3<<<NQ / 4, 256, 0, stream>>>(valueH, proj, refpts, oatH);

    gemm_out<<<NQBLK, 256, 0, stream>>>(oatH, wuT, b_out, (float*)d_out);
}

// Round 9
// 63.849 us; speedup vs baseline: 1.4048x; 1.0777x over previous
//
#include <hip/hip_runtime.h>
#include <hip/hip_bf16.h>

#define NQ     4000
#define DMODEL 256
#define NHEAD  8
#define NLVL   4
#define NPT    4
#define DHEAD  32
#define LENIN  37440
#define NOFF   384
#define NATT   128
#define NPROJ  512   // NOFF + NATT

#define NVBLK  (LENIN / 64)            // 585 value-role blocks
#define NQBLK  ((NQ + 63) / 64)        // 63 row tiles for query-side GEMMs
#define LDH    40                      // padded LDS row (halfs) for GEMM tiles
#define LDSW   132                     // padded LDS row (halfs) for C bounce

typedef _Float16 f16x8 __attribute__((ext_vector_type(8)));
typedef _Float16 f16x4 __attribute__((ext_vector_type(4)));
typedef float    f32x4 __attribute__((ext_vector_type(4)));

// ------------------------------------- all weight casts+transposes, 1 launch
__global__ __launch_bounds__(256) void cast_transpose_all(
    const float* __restrict__ wv, const float* __restrict__ wo,
    const float* __restrict__ wa, const float* __restrict__ wu,
    _Float16* __restrict__ wvT, _Float16* __restrict__ catT,
    _Float16* __restrict__ wuT)
{
    __shared__ float t[64][65];
    const int xt = blockIdx.x, kt = blockIdx.y;
    const float* W; _Float16* WT; int ncols, col0, nbase;
    if (xt < 4)       { W = wv; WT = wvT;  ncols = 256; col0 = xt * 64;        nbase = col0; }
    else if (xt < 10) { W = wo; WT = catT; ncols = 384; col0 = (xt - 4) * 64;  nbase = col0; }
    else if (xt < 12) { W = wa; WT = catT; ncols = 128; col0 = (xt - 10) * 64; nbase = 384 + col0; }
    else              { W = wu; WT = wuT;  ncols = 256; col0 = (xt - 12) * 64; nbase = col0; }

    const int by = kt * 64;           // k-range
    const int tid = threadIdx.x;
    const int c = tid & 63, r0 = tid >> 6;
    #pragma unroll
    for (int i = 0; i < 16; ++i) {
        int r = r0 + i * 4;
        t[r][c] = W[(size_t)(by + r) * ncols + col0 + c];
    }
    __syncthreads();
    #pragma unroll
    for (int i = 0; i < 16; ++i) {
        int n = r0 + i * 4;
        WT[(size_t)(nbase + n) * DMODEL + by + c] = (_Float16)t[c][n];
    }
}

// -------------------------------------------- merged front GEMM (fp32 input)
// Role A (bid < NVBLK):  valueH(f16, head-major) = input_flatten @ wvT^T + bv
//                        epilogue via LDS bounce -> coalesced stores.
// Role B (bid >= NVBLK): proj(f16) = query @ catT^T + [b_off|b_attn].
__global__ __launch_bounds__(256) void gemm_front(
    const float* __restrict__ Aval, const float* __restrict__ query,
    const _Float16* __restrict__ wvT, const _Float16* __restrict__ catT,
    const float* __restrict__ bval, const float* __restrict__ boff,
    const float* __restrict__ batt,
    _Float16* __restrict__ valueH, _Float16* __restrict__ proj)
{
    __shared__ __align__(16) char smem[25600];
    _Float16 (*As)[LDH] = (_Float16 (*)[LDH])smem;                 // 64 x 40
    _Float16 (*Bs)[LDH] = (_Float16 (*)[LDH])(smem + 64 * LDH * 2);// 256 x 40

    const int tid  = threadIdx.x;
    const int wave = tid >> 6, lane = tid & 63;
    const int l15 = lane & 15, l16 = lane >> 4;

    const int  bid   = blockIdx.x;
    const bool isval = (bid < NVBLK);
    const float* A; const _Float16* BT; int brow, ncb, M;
    if (isval) { A = Aval;  BT = wvT;  brow = bid * 64;  ncb = 0;  M = LENIN; }
    else       { int idx = bid - NVBLK; A = query; BT = catT;
                 brow = (idx >> 1) * 64; ncb = (idx & 1) * 256; M = NQ; }

    const int arow = tid >> 2, akq = (tid & 3) * 8;
    int arg = brow + arow; if (arg >= M) arg = M - 1;
    const float* aptr = A + (size_t)arg * DMODEL + akq;

    const _Float16* bptr[4];
    int bn[4], bkc[4];
    #pragma unroll
    for (int j = 0; j < 4; ++j) {
        int id = tid + 256 * j;            // chunk id = n*4 + kc
        bn[j] = id >> 2; bkc[j] = (id & 3) * 8;
        bptr[j] = BT + (size_t)(ncb + bn[j]) * DMODEL + bkc[j];
    }

    f32x4 acc[4][4] = {};   // [mi][ni]
    float4 a0, a1;
    f16x8 bh[4];

    a0 = *(const float4*)(const void*)aptr;
    a1 = *(const float4*)(const void*)(aptr + 4);
    #pragma unroll
    for (int j = 0; j < 4; ++j) bh[j] = *(const f16x8*)bptr[j];

    for (int k0 = 0; k0 < DMODEL; k0 += 32) {
        {
            f16x8 h;
            h[0] = (_Float16)a0.x; h[1] = (_Float16)a0.y;
            h[2] = (_Float16)a0.z; h[3] = (_Float16)a0.w;
            h[4] = (_Float16)a1.x; h[5] = (_Float16)a1.y;
            h[6] = (_Float16)a1.z; h[7] = (_Float16)a1.w;
            *(f16x8*)&As[arow][akq] = h;
        }
        #pragma unroll
        for (int j = 0; j < 4; ++j) *(f16x8*)&Bs[bn[j]][bkc[j]] = bh[j];
        __syncthreads();

        if (k0 + 32 < DMODEL) {   // issue next K-step's loads before MFMA
            a0 = *(const float4*)(const void*)(aptr + k0 + 32);
            a1 = *(const float4*)(const void*)(aptr + k0 + 36);
            #pragma unroll
            for (int j = 0; j < 4; ++j) bh[j] = *(const f16x8*)(bptr[j] + k0 + 32);
        }

        f16x8 af[4], bf[4];
        #pragma unroll
        for (int mi = 0; mi < 4; ++mi)
            af[mi] = *(const f16x8*)&As[mi * 16 + l15][l16 * 8];
        #pragma unroll
        for (int ni = 0; ni < 4; ++ni)
            bf[ni] = *(const f16x8*)&Bs[wave * 64 + ni * 16 + l15][l16 * 8];
        #pragma unroll
        for (int mi = 0; mi < 4; ++mi)
            #pragma unroll
            for (int ni = 0; ni < 4; ++ni)
                acc[mi][ni] = __builtin_amdgcn_mfma_f32_16x16x32_f16(
                    af[mi], bf[ni], acc[mi][ni], 0, 0, 0);
        __syncthreads();
    }

    if (isval) {
        // ---- epilogue A: LDS bounce -> coalesced head-major stores
        _Float16 (*out_s)[LDSW] = (_Float16 (*)[LDSW])smem;
        const int cell = tid >> 2, dchunk = tid & 3;
        #pragma unroll
        for (int hh = 0; hh < 2; ++hh) {
            if ((wave >> 1) == hh) {
                int cb = (wave & 1) * 64;
                #pragma unroll
                for (int ni = 0; ni < 4; ++ni) {
                    int col = wave * 64 + ni * 16 + l15;
                    float b = bval[col];
                    #pragma unroll
                    for (int mi = 0; mi < 4; ++mi)
                        #pragma unroll
                        for (int j = 0; j < 4; ++j)
                            out_s[mi * 16 + l16 * 4 + j][cb + ni * 16 + l15] =
                                (_Float16)(acc[mi][ni][j] + b);
                }
            }
            __syncthreads();
            #pragma unroll
            for (int h2 = 0; h2 < 4; ++h2) {
                int h = hh * 4 + h2;
                f16x4 lo = *(const f16x4*)&out_s[cell][h2 * 32 + dchunk * 8];
                f16x4 hi = *(const f16x4*)&out_s[cell][h2 * 32 + dchunk * 8 + 4];
                size_t base = ((size_t)h * LENIN + brow + cell) * DHEAD + dchunk * 8;
                *(f16x4*)&valueH[base]     = lo;
                *(f16x4*)&valueH[base + 4] = hi;
            }
            __syncthreads();
        }
    } else {
        // ---- epilogue B: f16 stores to proj
        #pragma unroll
        for (int ni = 0; ni < 4; ++ni) {
            int col = ncb + wave * 64 + ni * 16 + l15;
            float b = (col < NOFF) ? boff[col] : batt[col - NOFF];
            #pragma unroll
            for (int mi = 0; mi < 4; ++mi)
                #pragma unroll
                for (int j = 0; j < 4; ++j) {
                    int row = brow + mi * 16 + l16 * 4 + j;
                    if (row < NQ)
                        proj[(size_t)row * NPROJ + col] = (_Float16)(acc[mi][ni][j] + b);
                }
        }
    }
}

// ---------------- fused: loc + softmax + corner precompute + gather (4 q/blk)
// One wave per query. value is head-major: [h][cell][32ch] f16.
__global__ __launch_bounds__(256) void sample_fused3(
    const _Float16* __restrict__ value, const _Float16* __restrict__ proj,
    const float* __restrict__ refpts, _Float16* __restrict__ oat)
{
    __shared__ float loc_s[4][NOFF];
    __shared__ float aw_s[4][NATT];
    __shared__ uint2 cw_s[4][1056];     // [h*132 + pt*8 + c]

    const int tid  = threadIdx.x;
    const int wv   = tid >> 6, lane = tid & 63;
    const int q    = blockIdx.x * 4 + wv;
    const _Float16* pq = proj + (size_t)q * NPROJ;

    // ---- phase 0: locations + softmax
    #pragma unroll
    for (int i = 0; i < 8; ++i) {
        int t = i * 64 + lane;
        float v = (float)pq[t];
        if (t < NOFF) {
            int t2 = t / 3, lvl = (t2 >> 2) & 3, c = t - t2 * 3;
            float norm = (float)(32 >> lvl);
            loc_s[wv][t] = refpts[((size_t)q * NLVL + lvl) * 3 + c] + v / norm;
        } else {
            float m = v;
            #pragma unroll
            for (int o = 8; o >= 1; o >>= 1) m = fmaxf(m, __shfl_xor(m, o, 16));
            float e = expf(v - m);
            float s = e;
            #pragma unroll
            for (int o = 8; o >= 1; o >>= 1) s += __shfl_xor(s, o, 16);
            aw_s[wv][t - NOFF] = e / s;
        }
    }
    __syncthreads();

    // ---- phase 1: per-corner byte address (head-major) + weight
    #pragma unroll
    for (int i = 0; i < 16; ++i) {
        int id = i * 64 + lane;            // h*128 + pt*8 + c
        int h = id >> 7, pt = (id >> 3) & 15, c = id & 7;
        int lvl = pt >> 2;
        int S = 32 >> lvl;
        float Sf = (float)S;
        int base = (lvl == 0) ? 0 : (lvl == 1) ? 32768 : (lvl == 2) ? 36864 : 37376;

        float lx = loc_s[wv][h * 48 + pt * 3 + 0];
        float ly = loc_s[wv][h * 48 + pt * 3 + 1];
        float lz = loc_s[wv][h * 48 + pt * 3 + 2];
        float aw = aw_s[wv][h * 16 + pt];

        float x = lx * Sf - 0.5f, y = ly * Sf - 0.5f, z = lz * Sf - 0.5f;
        float x0f = floorf(x), y0f = floorf(y), z0f = floorf(z);
        float fx = x - x0f, fy = y - y0f, fz = z - z0f;
        int dx = c & 1, dy = (c >> 1) & 1, dz = c >> 2;
        int xi = (int)x0f + dx, yi = (int)y0f + dy, zi = (int)z0f + dz;
        float wx = dx ? fx : 1.f - fx;
        float wy = dy ? fy : 1.f - fy;
        float wz = dz ? fz : 1.f - fz;
        bool valid = (unsigned)xi < (unsigned)S &&
                     (unsigned)yi < (unsigned)S &&
                     (unsigned)zi < (unsigned)S;
        float w = valid ? wx * wy * wz * aw : 0.f;
        int xc = min(max(xi, 0), S - 1);
        int yc = min(max(yi, 0), S - 1);
        int zc = min(max(zi, 0), S - 1);
        int idx = (zc * S + yc) * S + xc;
        unsigned addr = (unsigned)(h * LENIN + base + idx) * 64u;  // bytes
        cw_s[wv][h * 132 + pt * 8 + c] = make_uint2(addr, __float_as_uint(w));
    }
    __syncthreads();

    // ---- phase 2: gather, 16B per load
    const int h = lane >> 3, s = lane & 7;
    const int chunk = s & 3, half4 = (s >> 2) * 4;
    const char* vb = (const char*)value + chunk * 16;
    const uint2* cw = &cw_s[wv][h * 132];

    float acc[8] = {};
    #pragma unroll 4
    for (int pt = 0; pt < 16; ++pt) {
        uint4 ra = *(const uint4*)&cw[pt * 8 + half4];       // corners half4+0,+1
        uint4 rb = *(const uint4*)&cw[pt * 8 + half4 + 2];   // corners half4+2,+3
        {
            f16x8 v = *(const f16x8*)(vb + ra.x); float w = __uint_as_float(ra.y);
            #pragma unroll
            for (int j = 0; j < 8; ++j) acc[j] += w * (float)v[j];
        }
        {
            f16x8 v = *(const f16x8*)(vb + ra.z); float w = __uint_as_float(ra.w);
            #pragma unroll
            for (int j = 0; j < 8; ++j) acc[j] += w * (float)v[j];
        }
        {
            f16x8 v = *(const f16x8*)(vb + rb.x); float w = __uint_as_float(rb.y);
            #pragma unroll
            for (int j = 0; j < 8; ++j) acc[j] += w * (float)v[j];
        }
        {
            f16x8 v = *(const f16x8*)(vb + rb.z); float w = __uint_as_float(rb.w);
            #pragma unroll
            for (int j = 0; j < 8; ++j) acc[j] += w * (float)v[j];
        }
    }
    // combine the two corner-halves (lanes s and s^4 own same channels)
    #pragma unroll
    for (int j = 0; j < 8; ++j) acc[j] += __shfl_xor(acc[j], 4);

    if (s < 4) {
        f16x8 r;
        #pragma unroll
        for (int j = 0; j < 8; ++j) r[j] = (_Float16)acc[j];
        *(f16x8*)&oat[(size_t)q * DMODEL + h * DHEAD + chunk * 8] = r;
    }
}

// ---------------------- output projection (f16 in, MFMA, 64x128 per block)
__global__ __launch_bounds__(256) void gemm_out(
    const _Float16* __restrict__ A, const _Float16* __restrict__ BT,
    const float* __restrict__ bias, float* __restrict__ C)
{
    __shared__ __align__(16) _Float16 As[64][LDH];
    __shared__ __align__(16) _Float16 Bs[128][LDH];
    const int tid  = threadIdx.x;
    const int wave = tid >> 6, lane = tid & 63;
    const int brow = blockIdx.x * 64;
    const int bcol = blockIdx.y * 128;
    const int l15 = lane & 15, l16 = lane >> 4;

    const int arow = tid >> 2, akq = (tid & 3) * 8;
    int arg = brow + arow; if (arg >= NQ) arg = NQ - 1;
    const _Float16* aptr = A + (size_t)arg * DMODEL + akq;

    const _Float16* bptr[2];
    int bn[2], bkc[2];
    #pragma unroll
    for (int j = 0; j < 2; ++j) {
        int id = tid + 256 * j;
        bn[j] = id >> 2; bkc[j] = (id & 3) * 8;
        bptr[j] = BT + (size_t)(bcol + bn[j]) * DMODEL + bkc[j];
    }

    f32x4 acc[4][2] = {};
    f16x8 ah, bh[2];
    ah = *(const f16x8*)(const void*)aptr;
    #pragma unroll
    for (int j = 0; j < 2; ++j) bh[j] = *(const f16x8*)bptr[j];

    for (int k0 = 0; k0 < DMODEL; k0 += 32) {
        *(f16x8*)&As[arow][akq] = ah;
        #pragma unroll
        for (int j = 0; j < 2; ++j) *(f16x8*)&Bs[bn[j]][bkc[j]] = bh[j];
        __syncthreads();

        if (k0 + 32 < DMODEL) {
            ah = *(const f16x8*)(const void*)(aptr + k0 + 32);
            #pragma unroll
            for (int j = 0; j < 2; ++j) bh[j] = *(const f16x8*)(bptr[j] + k0 + 32);
        }

        f16x8 af[4], bf[2];
        #pragma unroll
        for (int mi = 0; mi < 4; ++mi)
            af[mi] = *(const f16x8*)&As[mi * 16 + l15][l16 * 8];
        #pragma unroll
        for (int ni = 0; ni < 2; ++ni)
            bf[ni] = *(const f16x8*)&Bs[wave * 32 + ni * 16 + l15][l16 * 8];
        #pragma unroll
        for (int mi = 0; mi < 4; ++mi)
            #pragma unroll
            for (int ni = 0; ni < 2; ++ni)
                acc[mi][ni] = __builtin_amdgcn_mfma_f32_16x16x32_f16(
                    af[mi], bf[ni], acc[mi][ni], 0, 0, 0);
        __syncthreads();
    }

    #pragma unroll
    for (int ni = 0; ni < 2; ++ni) {
        int col = bcol + wave * 32 + ni * 16 + l15;
        float b = bias[col];
        #pragma unroll
        for (int mi = 0; mi < 4; ++mi)
            #pragma unroll
            for (int j = 0; j < 4; ++j) {
                int row = brow + mi * 16 + l16 * 4 + j;
                if (row < NQ)
                    C[(size_t)row * DMODEL + col] = acc[mi][ni][j] + b;
            }
    }
}

extern "C" void kernel_launch(void* const* d_in, const int* in_sizes, int n_in,
                              void* d_out, int out_size, void* d_ws, size_t ws_size,
                              hipStream_t stream) {
    const float* query         = (const float*)d_in[0];
    const float* refpts        = (const float*)d_in[1];
    const float* input_flatten = (const float*)d_in[2];
    const float* w_value       = (const float*)d_in[3];
    const float* b_value       = (const float*)d_in[4];
    const float* w_off         = (const float*)d_in[5];
    const float* b_off         = (const float*)d_in[6];
    const float* w_attn        = (const float*)d_in[7];
    const float* b_attn        = (const float*)d_in[8];
    const float* w_out         = (const float*)d_in[9];
    const float* b_out         = (const float*)d_in[10];

    _Float16* valueH = (_Float16*)d_ws;                    // head-major [h][cell][32]
    _Float16* wvT    = valueH + (size_t)LENIN * DMODEL;
    _Float16* catT   = wvT + 256 * 256;
    _Float16* wuT    = catT + 512 * 256;
    _Float16* proj   = wuT + 256 * 256;                    // f16 [NQ][512]
    _Float16* oatH   = proj + (size_t)NQ * NPROJ;
    // total ~26 MB of workspace

    cast_transpose_all<<<dim3(16, 4), 256, 0, stream>>>(
        w_value, w_off, w_attn, w_out, wvT, catT, wuT);

    gemm_front<<<NVBLK + NQBLK * 2, 256, 0, stream>>>(
        input_flatten, query, wvT, catT, b_value, b_off, b_attn, valueH, proj);

    sample_fused3<<<NQ / 4, 256, 0, stream>>>(valueH, proj, refpts, oatH);

    gemm_out<<<dim3(NQBLK, 2), 256, 0, stream>>>(oatH, wuT, b_out, (float*)d_out);
}

// Round 10
// 63.567 us; speedup vs baseline: 1.4110x; 1.0044x over previous
//
#include <hip/hip_runtime.h>
#include <hip/hip_bf16.h>

#define NQ     4000
#define DMODEL 256
#define NHEAD  8
#define NLVL   4
#define NPT    4
#define DHEAD  32
#define LENIN  37440
#define NOFF   384
#define NATT   128
#define NPROJ  512   // NOFF + NATT

#define NVBLK  (LENIN / 64)            // 585 value-role blocks
#define NQBLK  ((NQ + 63) / 64)        // 63 row tiles for query-side GEMMs
#define LDH    40                      // padded LDS row (halfs) for GEMM tiles
#define LDSW   132                     // padded LDS row (halfs) for C bounce

typedef _Float16 f16x8 __attribute__((ext_vector_type(8)));
typedef _Float16 f16x4 __attribute__((ext_vector_type(4)));
typedef float    f32x4 __attribute__((ext_vector_type(4)));

// ------------------------------------- all weight casts+transposes, 1 launch
__global__ __launch_bounds__(256) void cast_transpose_all(
    const float* __restrict__ wv, const float* __restrict__ wo,
    const float* __restrict__ wa, const float* __restrict__ wu,
    _Float16* __restrict__ wvT, _Float16* __restrict__ catT,
    _Float16* __restrict__ wuT)
{
    __shared__ float t[64][65];
    const int xt = blockIdx.x, kt = blockIdx.y;
    const float* W; _Float16* WT; int ncols, col0, nbase;
    if (xt < 4)       { W = wv; WT = wvT;  ncols = 256; col0 = xt * 64;        nbase = col0; }
    else if (xt < 10) { W = wo; WT = catT; ncols = 384; col0 = (xt - 4) * 64;  nbase = col0; }
    else if (xt < 12) { W = wa; WT = catT; ncols = 128; col0 = (xt - 10) * 64; nbase = 384 + col0; }
    else              { W = wu; WT = wuT;  ncols = 256; col0 = (xt - 12) * 64; nbase = col0; }

    const int by = kt * 64;           // k-range
    const int tid = threadIdx.x;
    const int c = tid & 63, r0 = tid >> 6;
    #pragma unroll
    for (int i = 0; i < 16; ++i) {
        int r = r0 + i * 4;
        t[r][c] = W[(size_t)(by + r) * ncols + col0 + c];
    }
    __syncthreads();
    #pragma unroll
    for (int i = 0; i < 16; ++i) {
        int n = r0 + i * 4;
        WT[(size_t)(nbase + n) * DMODEL + by + c] = (_Float16)t[c][n];
    }
}

// -------------------------------------------- merged front GEMM (fp32 input)
// Role A (bid < NVBLK):  valueH(f16, head-major) = input_flatten @ wvT^T + bv
//                        epilogue via LDS bounce -> coalesced stores.
// Role B (bid >= NVBLK): proj(f16) = query @ catT^T + [b_off|b_attn].
__global__ __launch_bounds__(256) void gemm_front(
    const float* __restrict__ Aval, const float* __restrict__ query,
    const _Float16* __restrict__ wvT, const _Float16* __restrict__ catT,
    const float* __restrict__ bval, const float* __restrict__ boff,
    const float* __restrict__ batt,
    _Float16* __restrict__ valueH, _Float16* __restrict__ proj)
{
    __shared__ __align__(16) char smem[25600];
    _Float16 (*As)[LDH] = (_Float16 (*)[LDH])smem;                 // 64 x 40
    _Float16 (*Bs)[LDH] = (_Float16 (*)[LDH])(smem + 64 * LDH * 2);// 256 x 40

    const int tid  = threadIdx.x;
    const int wave = tid >> 6, lane = tid & 63;
    const int l15 = lane & 15, l16 = lane >> 4;

    const int  bid   = blockIdx.x;
    const bool isval = (bid < NVBLK);
    const float* A; const _Float16* BT; int brow, ncb, M;
    if (isval) { A = Aval;  BT = wvT;  brow = bid * 64;  ncb = 0;  M = LENIN; }
    else       { int idx = bid - NVBLK; A = query; BT = catT;
                 brow = (idx >> 1) * 64; ncb = (idx & 1) * 256; M = NQ; }

    const int arow = tid >> 2, akq = (tid & 3) * 8;
    int arg = brow + arow; if (arg >= M) arg = M - 1;
    const float* aptr = A + (size_t)arg * DMODEL + akq;

    const _Float16* bptr[4];
    int bn[4], bkc[4];
    #pragma unroll
    for (int j = 0; j < 4; ++j) {
        int id = tid + 256 * j;            // chunk id = n*4 + kc
        bn[j] = id >> 2; bkc[j] = (id & 3) * 8;
        bptr[j] = BT + (size_t)(ncb + bn[j]) * DMODEL + bkc[j];
    }

    f32x4 acc[4][4] = {};   // [mi][ni]
    float4 a0, a1;
    f16x8 bh[4];

    a0 = *(const float4*)(const void*)aptr;
    a1 = *(const float4*)(const void*)(aptr + 4);
    #pragma unroll
    for (int j = 0; j < 4; ++j) bh[j] = *(const f16x8*)bptr[j];

    for (int k0 = 0; k0 < DMODEL; k0 += 32) {
        {
            f16x8 h;
            h[0] = (_Float16)a0.x; h[1] = (_Float16)a0.y;
            h[2] = (_Float16)a0.z; h[3] = (_Float16)a0.w;
            h[4] = (_Float16)a1.x; h[5] = (_Float16)a1.y;
            h[6] = (_Float16)a1.z; h[7] = (_Float16)a1.w;
            *(f16x8*)&As[arow][akq] = h;
        }
        #pragma unroll
        for (int j = 0; j < 4; ++j) *(f16x8*)&Bs[bn[j]][bkc[j]] = bh[j];
        __syncthreads();

        if (k0 + 32 < DMODEL) {   // issue next K-step's loads before MFMA
            a0 = *(const float4*)(const void*)(aptr + k0 + 32);
            a1 = *(const float4*)(const void*)(aptr + k0 + 36);
            #pragma unroll
            for (int j = 0; j < 4; ++j) bh[j] = *(const f16x8*)(bptr[j] + k0 + 32);
        }

        f16x8 af[4], bf[4];
        #pragma unroll
        for (int mi = 0; mi < 4; ++mi)
            af[mi] = *(const f16x8*)&As[mi * 16 + l15][l16 * 8];
        #pragma unroll
        for (int ni = 0; ni < 4; ++ni)
            bf[ni] = *(const f16x8*)&Bs[wave * 64 + ni * 16 + l15][l16 * 8];
        #pragma unroll
        for (int mi = 0; mi < 4; ++mi)
            #pragma unroll
            for (int ni = 0; ni < 4; ++ni)
                acc[mi][ni] = __builtin_amdgcn_mfma_f32_16x16x32_f16(
                    af[mi], bf[ni], acc[mi][ni], 0, 0, 0);
        __syncthreads();
    }

    if (isval) {
        // ---- epilogue A: LDS bounce -> coalesced head-major stores
        _Float16 (*out_s)[LDSW] = (_Float16 (*)[LDSW])smem;
        const int cell = tid >> 2, dchunk = tid & 3;
        #pragma unroll
        for (int hh = 0; hh < 2; ++hh) {
            if ((wave >> 1) == hh) {
                int cb = (wave & 1) * 64;
                #pragma unroll
                for (int ni = 0; ni < 4; ++ni) {
                    int col = wave * 64 + ni * 16 + l15;
                    float b = bval[col];
                    #pragma unroll
                    for (int mi = 0; mi < 4; ++mi)
                        #pragma unroll
                        for (int j = 0; j < 4; ++j)
                            out_s[mi * 16 + l16 * 4 + j][cb + ni * 16 + l15] =
                                (_Float16)(acc[mi][ni][j] + b);
                }
            }
            __syncthreads();
            #pragma unroll
            for (int h2 = 0; h2 < 4; ++h2) {
                int h = hh * 4 + h2;
                f16x4 lo = *(const f16x4*)&out_s[cell][h2 * 32 + dchunk * 8];
                f16x4 hi = *(const f16x4*)&out_s[cell][h2 * 32 + dchunk * 8 + 4];
                size_t base = ((size_t)h * LENIN + brow + cell) * DHEAD + dchunk * 8;
                *(f16x4*)&valueH[base]     = lo;
                *(f16x4*)&valueH[base + 4] = hi;
            }
            __syncthreads();
        }
    } else {
        // ---- epilogue B: f16 stores to proj
        #pragma unroll
        for (int ni = 0; ni < 4; ++ni) {
            int col = ncb + wave * 64 + ni * 16 + l15;
            float b = (col < NOFF) ? boff[col] : batt[col - NOFF];
            #pragma unroll
            for (int mi = 0; mi < 4; ++mi)
                #pragma unroll
                for (int j = 0; j < 4; ++j) {
                    int row = brow + mi * 16 + l16 * 4 + j;
                    if (row < NQ)
                        proj[(size_t)row * NPROJ + col] = (_Float16)(acc[mi][ni][j] + b);
                }
        }
    }
}

// ---------------- fused: loc + softmax + corner precompute + gather (4 q/blk)
// One wave per query. value is head-major: [h][cell][32ch] f16.
// Corner table split into uint addr + f16 weight (LDS 42->33.5KB: 4 blk/CU).
// OOB corners: addr -> cell 0 of same head (hot line), weight 0.
__global__ __launch_bounds__(256) void sample_fused4(
    const _Float16* __restrict__ value, const _Float16* __restrict__ proj,
    const float* __restrict__ refpts, _Float16* __restrict__ oat)
{
    __shared__ float    loc_s[4][NOFF];
    __shared__ float    aw_s[4][NATT];
    __shared__ unsigned ca_s[4][1056];      // [h*132 + pt*8 + c] byte addr
    __shared__ _Float16 cw_s[4][1056];      // [h*132 + pt*8 + c] weight

    const int tid  = threadIdx.x;
    const int wv   = tid >> 6, lane = tid & 63;
    const int q    = blockIdx.x * 4 + wv;
    const _Float16* pq = proj + (size_t)q * NPROJ;

    // ---- phase 0: locations + softmax
    #pragma unroll
    for (int i = 0; i < 8; ++i) {
        int t = i * 64 + lane;
        float v = (float)pq[t];
        if (t < NOFF) {
            int t2 = t / 3, lvl = (t2 >> 2) & 3, c = t - t2 * 3;
            float norm = (float)(32 >> lvl);
            loc_s[wv][t] = refpts[((size_t)q * NLVL + lvl) * 3 + c] + v / norm;
        } else {
            float m = v;
            #pragma unroll
            for (int o = 8; o >= 1; o >>= 1) m = fmaxf(m, __shfl_xor(m, o, 16));
            float e = expf(v - m);
            float s = e;
            #pragma unroll
            for (int o = 8; o >= 1; o >>= 1) s += __shfl_xor(s, o, 16);
            aw_s[wv][t - NOFF] = e / s;
        }
    }
    __syncthreads();

    // ---- phase 1: per-corner byte address (head-major) + weight
    #pragma unroll
    for (int i = 0; i < 16; ++i) {
        int id = i * 64 + lane;            // h*128 + pt*8 + c
        int h = id >> 7, pt = (id >> 3) & 15, c = id & 7;
        int lvl = pt >> 2;
        int S = 32 >> lvl;
        float Sf = (float)S;
        int base = (lvl == 0) ? 0 : (lvl == 1) ? 32768 : (lvl == 2) ? 36864 : 37376;

        float lx = loc_s[wv][h * 48 + pt * 3 + 0];
        float ly = loc_s[wv][h * 48 + pt * 3 + 1];
        float lz = loc_s[wv][h * 48 + pt * 3 + 2];
        float aw = aw_s[wv][h * 16 + pt];

        float x = lx * Sf - 0.5f, y = ly * Sf - 0.5f, z = lz * Sf - 0.5f;
        float x0f = floorf(x), y0f = floorf(y), z0f = floorf(z);
        float fx = x - x0f, fy = y - y0f, fz = z - z0f;
        int dx = c & 1, dy = (c >> 1) & 1, dz = c >> 2;
        int xi = (int)x0f + dx, yi = (int)y0f + dy, zi = (int)z0f + dz;
        float wx = dx ? fx : 1.f - fx;
        float wy = dy ? fy : 1.f - fy;
        float wz = dz ? fz : 1.f - fz;
        bool valid = (unsigned)xi < (unsigned)S &&
                     (unsigned)yi < (unsigned)S &&
                     (unsigned)zi < (unsigned)S;
        int idx = (zi * S + yi) * S + xi;            // only meaningful if valid
        unsigned addr = valid ? (unsigned)(h * LENIN + base + idx) * 64u
                              : (unsigned)(h * LENIN) * 64u;   // hot dummy line
        float w = valid ? wx * wy * wz * aw : 0.f;
        ca_s[wv][h * 132 + pt * 8 + c] = addr;
        cw_s[wv][h * 132 + pt * 8 + c] = (_Float16)w;
    }
    __syncthreads();

    // ---- phase 2: gather, 16B per load
    const int h = lane >> 3, s = lane & 7;
    const int chunk = s & 3, half4 = (s >> 2) * 4;
    const char* vb = (const char*)value + chunk * 16;
    const unsigned* ca = &ca_s[wv][h * 132];
    const _Float16* cwp = &cw_s[wv][h * 132];

    float acc[8] = {};
    #pragma unroll 4
    for (int pt = 0; pt < 16; ++pt) {
        uint4 a4 = *(const uint4*)&ca[pt * 8 + half4];
        f16x4 w4 = *(const f16x4*)&cwp[pt * 8 + half4];
        {
            f16x8 v = *(const f16x8*)(vb + a4.x); float w = (float)w4[0];
            #pragma unroll
            for (int j = 0; j < 8; ++j) acc[j] += w * (float)v[j];
        }
        {
            f16x8 v = *(const f16x8*)(vb + a4.y); float w = (float)w4[1];
            #pragma unroll
            for (int j = 0; j < 8; ++j) acc[j] += w * (float)v[j];
        }
        {
            f16x8 v = *(const f16x8*)(vb + a4.z); float w = (float)w4[2];
            #pragma unroll
            for (int j = 0; j < 8; ++j) acc[j] += w * (float)v[j];
        }
        {
            f16x8 v = *(const f16x8*)(vb + a4.w); float w = (float)w4[3];
            #pragma unroll
            for (int j = 0; j < 8; ++j) acc[j] += w * (float)v[j];
        }
    }
    // combine the two corner-halves (lanes s and s^4 own same channels)
    #pragma unroll
    for (int j = 0; j < 8; ++j) acc[j] += __shfl_xor(acc[j], 4);

    if (s < 4) {
        f16x8 r;
        #pragma unroll
        for (int j = 0; j < 8; ++j) r[j] = (_Float16)acc[j];
        *(f16x8*)&oat[(size_t)q * DMODEL + h * DHEAD + chunk * 8] = r;
    }
}

// ---------------------- output projection (f16 in, MFMA, 64x128 per block)
__global__ __launch_bounds__(256) void gemm_out(
    const _Float16* __restrict__ A, const _Float16* __restrict__ BT,
    const float* __restrict__ bias, float* __restrict__ C)
{
    __shared__ __align__(16) _Float16 As[64][LDH];
    __shared__ __align__(16) _Float16 Bs[128][LDH];
    const int tid  = threadIdx.x;
    const int wave = tid >> 6, lane = tid & 63;
    const int brow = blockIdx.x * 64;
    const int bcol = blockIdx.y * 128;
    const int l15 = lane & 15, l16 = lane >> 4;

    const int arow = tid >> 2, akq = (tid & 3) * 8;
    int arg = brow + arow; if (arg >= NQ) arg = NQ - 1;
    const _Float16* aptr = A + (size_t)arg * DMODEL + akq;

    const _Float16* bptr[2];
    int bn[2], bkc[2];
    #pragma unroll
    for (int j = 0; j < 2; ++j) {
        int id = tid + 256 * j;
        bn[j] = id >> 2; bkc[j] = (id & 3) * 8;
        bptr[j] = BT + (size_t)(bcol + bn[j]) * DMODEL + bkc[j];
    }

    f32x4 acc[4][2] = {};
    f16x8 ah, bh[2];
    ah = *(const f16x8*)(const void*)aptr;
    #pragma unroll
    for (int j = 0; j < 2; ++j) bh[j] = *(const f16x8*)bptr[j];

    for (int k0 = 0; k0 < DMODEL; k0 += 32) {
        *(f16x8*)&As[arow][akq] = ah;
        #pragma unroll
        for (int j = 0; j < 2; ++j) *(f16x8*)&Bs[bn[j]][bkc[j]] = bh[j];
        __syncthreads();

        if (k0 + 32 < DMODEL) {
            ah = *(const f16x8*)(const void*)(aptr + k0 + 32);
            #pragma unroll
            for (int j = 0; j < 2; ++j) bh[j] = *(const f16x8*)(bptr[j] + k0 + 32);
        }

        f16x8 af[4], bf[2];
        #pragma unroll
        for (int mi = 0; mi < 4; ++mi)
            af[mi] = *(const f16x8*)&As[mi * 16 + l15][l16 * 8];
        #pragma unroll
        for (int ni = 0; ni < 2; ++ni)
            bf[ni] = *(const f16x8*)&Bs[wave * 32 + ni * 16 + l15][l16 * 8];
        #pragma unroll
        for (int mi = 0; mi < 4; ++mi)
            #pragma unroll
            for (int ni = 0; ni < 2; ++ni)
                acc[mi][ni] = __builtin_amdgcn_mfma_f32_16x16x32_f16(
                    af[mi], bf[ni], acc[mi][ni], 0, 0, 0);
        __syncthreads();
    }

    #pragma unroll
    for (int ni = 0; ni < 2; ++ni) {
        int col = bcol + wave * 32 + ni * 16 + l15;
        float b = bias[col];
        #pragma unroll
        for (int mi = 0; mi < 4; ++mi)
            #pragma unroll
            for (int j = 0; j < 4; ++j) {
                int row = brow + mi * 16 + l16 * 4 + j;
                if (row < NQ)
                    C[(size_t)row * DMODEL + col] = acc[mi][ni][j] + b;
            }
    }
}

extern "C" void kernel_launch(void* const* d_in, const int* in_sizes, int n_in,
                              void* d_out, int out_size, void* d_ws, size_t ws_size,
                              hipStream_t stream) {
    const float* query         = (const float*)d_in[0];
    const float* refpts        = (const float*)d_in[1];
    const float* input_flatten = (const float*)d_in[2];
    const float* w_value       = (const float*)d_in[3];
    const float* b_value       = (const float*)d_in[4];
    const float* w_off         = (const float*)d_in[5];
    const float* b_off         = (const float*)d_in[6];
    const float* w_attn        = (const float*)d_in[7];
    const float* b_attn        = (const float*)d_in[8];
    const float* w_out         = (const float*)d_in[9];
    const float* b_out         = (const float*)d_in[10];

    _Float16* valueH = (_Float16*)d_ws;                    // head-major [h][cell][32]
    _Float16* wvT    = valueH + (size_t)LENIN * DMODEL;
    _Float16* catT   = wvT + 256 * 256;
    _Float16* wuT    = catT + 512 * 256;
    _Float16* proj   = wuT + 256 * 256;                    // f16 [NQ][512]
    _Float16* oatH   = proj + (size_t)NQ * NPROJ;
    // total ~26 MB of workspace

    cast_transpose_all<<<dim3(16, 4), 256, 0, stream>>>(
        w_value, w_off, w_attn, w_out, wvT, catT, wuT);

    gemm_front<<<NVBLK + NQBLK * 2, 256, 0, stream>>>(
        input_flatten, query, wvT, catT, b_value, b_off, b_attn, valueH, proj);

    sample_fused4<<<NQ / 4, 256, 0, stream>>>(valueH, proj, refpts, oatH);

    gemm_out<<<dim3(NQBLK, 2), 256, 0, stream>>>(oatH, wuT, b_out, (float*)d_out);
}